// Round 12
// baseline (273.745 us; speedup 1.0000x reference)
//
#include <hip/hip_runtime.h>
#include <hip/hip_bf16.h>

// CausalSelfAttention on MI355X. fp32 in / fp32 out, bf16 MFMA compute.
// [0] merged cvt pre-pass: {x, w_qkv, w_out} -> bf16 (single launch)
// [1] QKV GEMM: 256x128 block tile, 4 waves (2x2), WAVE TILE 128x64 (acc[8][4]).
//     Rationale: at 64x64 wave tiles the kernel is LDS-read-BW-bound
//     ((WM+WN)/(WM*WN)=1/32 bytes/FLOP; per-CU LDS ~saturated, MfmaUtil 29%).
//     128x64 cuts LDS bytes/FLOP 25% and doubles FLOP/staged-byte -> ~MFMA-bound.
//     Counted-vmcnt single-barrier loop kept: barrier -> STAGE(t+1) -> vmcnt(6).
// [2] flash attention (FROZEN this round): 4-wave blocks, 32 q-rows/wave,
//     single-buffer K/V, balanced qt map, fused per-kt QK^T+softmax w/ masked
//     -subtile MFMA skip, 3-way mask classification, lsum via ones-MFMA,
//     v_perm V-transpose, rotated prefetch, setprio PV, PV st-skip
// [3] out projection via same kernel -> d_out fp32
// B=4 T=2048 C=1024 H=16 Dh=64.

#define D_MODEL 1024
#define N_HEADS 16
#define HEAD_DIM 64
#define SEQ 2048
#define BATCH 4

typedef __attribute__((ext_vector_type(8))) short bf16x8;
typedef __attribute__((ext_vector_type(4))) float f32x4;
typedef unsigned int uint;

__device__ __forceinline__ short f2bf(float f) {
    union { float f; uint i; } c; c.f = f;
    uint x = c.i;
    x += 0x7fffu + ((x >> 16) & 1u);   // RNE
    return (short)(x >> 16);
}
__device__ __forceinline__ uint pack2(float a, float b) {
    return (uint)(unsigned short)f2bf(a) | ((uint)(unsigned short)f2bf(b) << 16);
}
__device__ __forceinline__ uint asu(float f) { union { float f; uint i; } c; c.f = f; return c.i; }
// truncating pack of two f32 -> bf16x2 (single v_perm)
__device__ __forceinline__ uint packtr(float lo, float hi) {
    return __builtin_amdgcn_perm(asu(hi), asu(lo), 0x07060302u);
}

// async global->LDS, 16B per lane; LDS dest = wave-uniform base + lane*16
__device__ __forceinline__ void glds16(const void* g, void* l) {
    __builtin_amdgcn_global_load_lds(
        (const __attribute__((address_space(1))) uint*)g,
        (__attribute__((address_space(3))) uint*)l, 16, 0, 0);
}

// ---------- fp32 -> bf16, 3 sources -> contiguous dst ----------
__global__ __launch_bounds__(256) void cvt3_bf16(const float* __restrict__ s0,
                                                 const float* __restrict__ s1,
                                                 const float* __restrict__ s2,
                                                 short* __restrict__ dst,
                                                 int n0, int n01) {
    int i = blockIdx.x * 256 + threadIdx.x;    // vec4 index
    const float* src;
    int off;
    if (i < n0)       { src = s0; off = i; }
    else if (i < n01) { src = s1; off = i - n0; }
    else              { src = s2; off = i - n01; }
    float4 f = *(const float4*)(src + (size_t)off * 4);
    uint2 o; o.x = pack2(f.x, f.y); o.y = pack2(f.z, f.w);
    *(uint2*)(dst + (size_t)i * 4) = o;
}

// ---------- GEMM: C[M,N] = A[M,K]@B[N,K]^T + bias ----------
// Block tile 256 (M) x 128 (N), 256 threads = 4 waves in 2x2; wave tile 128x64.
// acc[8][4] f32x4 = 128 VGPR (R8 precedent: same acc + half-split = 104 VGPR).
// BK=32, dbuf LDS 48KB. Per tile: s_barrier (WAR) -> STAGE(t+1) 6 glds16 ->
// vmcnt(6) (tile t landed, t+1 in flight) -> frags -> 32 MFMA.
// MODE 0: fp32 out. MODE 1: bf16 scatter q/k/v [B,H,T,Dh].
template <int MODE>
__global__ __launch_bounds__(256, 2) void gemm_bt(
    const short* __restrict__ A, const short* __restrict__ B,
    const float* __restrict__ bias, float* __restrict__ Cp,
    int M, int N, int K,
    short* __restrict__ qp, short* __restrict__ kp, short* __restrict__ vp)
{
    __shared__ short As[2][256][32];   // unpadded: glds needs contiguous lane*16 dest
    __shared__ short Bs[2][128][32];
    const int tid = threadIdx.x;
    const int wave = tid >> 6, lane = tid & 63;
    const int quad = lane >> 4, l16 = lane & 15;
    const int wm = (wave >> 1) * 128;            // wave row base (2 waves in M)
    const int wn = (wave & 1) * 64;              // wave col base (2 waves in N)
    const int rowBase = blockIdx.y * 256;
    const int colBase = blockIdx.x * 128;

    // staging: lane covers row (lane>>2), 16B chunk (lane&3); wave w stages
    // A rows w*64..w*64+63 (4 glds16) and B rows w*32..w*32+31 (2 glds16)
    const short* gA = A + (size_t)(rowBase + wave * 64 + (lane >> 2)) * K + (lane & 3) * 8;
    const short* gB = B + (size_t)(colBase + wave * 32 + (lane >> 2)) * K + (lane & 3) * 8;

    f32x4 acc[8][4] = {};
    const int NT = K / 32;

#define GSTAGE(buf, k0)                                                  \
    {                                                                    \
        glds16(gA + (k0),                  &As[buf][wave * 64][0]);      \
        glds16(gA + (size_t)16 * K + (k0), &As[buf][wave * 64 + 16][0]); \
        glds16(gA + (size_t)32 * K + (k0), &As[buf][wave * 64 + 32][0]); \
        glds16(gA + (size_t)48 * K + (k0), &As[buf][wave * 64 + 48][0]); \
        glds16(gB + (k0),                  &Bs[buf][wave * 32][0]);      \
        glds16(gB + (size_t)16 * K + (k0), &Bs[buf][wave * 32 + 16][0]); \
    }

    GSTAGE(0, 0)

    for (int t = 0; t < NT; ++t) {
        const int cur = t & 1;
        __builtin_amdgcn_s_barrier();              // WAR rendezvous (no vm drain)
        __builtin_amdgcn_sched_barrier(0);
        if (t + 1 < NT) GSTAGE(cur ^ 1, (t + 1) * 32)   // fly across this iter
        __builtin_amdgcn_sched_barrier(0);
        if (t + 1 < NT) asm volatile("s_waitcnt vmcnt(6)" ::: "memory");
        else            asm volatile("s_waitcnt vmcnt(0)" ::: "memory");
        __builtin_amdgcn_sched_barrier(0);

        bf16x8 bfr[4];
#pragma unroll
        for (int ni = 0; ni < 4; ++ni)
            bfr[ni] = *(const bf16x8*)&Bs[cur][wn + ni * 16 + l16][quad * 8];

#pragma unroll
        for (int half = 0; half < 2; ++half) {
            bf16x8 af[4];
#pragma unroll
            for (int mi = 0; mi < 4; ++mi)
                af[mi] = *(const bf16x8*)&As[cur][wm + half * 64 + mi * 16 + l16][quad * 8];
            __builtin_amdgcn_s_setprio(1);
#pragma unroll
            for (int mi = 0; mi < 4; ++mi)
#pragma unroll
                for (int ni = 0; ni < 4; ++ni)
                    acc[half * 4 + mi][ni] = __builtin_amdgcn_mfma_f32_16x16x32_bf16(
                        af[mi], bfr[ni], acc[half * 4 + mi][ni], 0, 0, 0);
            __builtin_amdgcn_s_setprio(0);
        }
    }
#undef GSTAGE

    // epilogue: C/D frag layout row=quad*4+reg, col=l16
#pragma unroll
    for (int mi = 0; mi < 8; ++mi) {
#pragma unroll
        for (int ni = 0; ni < 4; ++ni) {
#pragma unroll
            for (int r = 0; r < 4; ++r) {
                int row = rowBase + wm + mi * 16 + quad * 4 + r;
                int col = colBase + wn + ni * 16 + l16;
                float v = acc[mi][ni][r] + bias[col];
                if (MODE == 0) {
                    Cp[(size_t)row * N + col] = v;
                } else {
                    int which = col >> 10;          // 0:q 1:k 2:v
                    int h = (col >> 6) & 15;
                    int d = col & 63;
                    int b = row >> 11;
                    int t2 = row & 2047;
                    short* dst = (which == 0) ? qp : (which == 1) ? kp : vp;
                    dst[((((size_t)b * N_HEADS + h) * SEQ) + t2) * HEAD_DIM + d] = f2bf(v);
                }
            }
        }
    }
}

// ---------- flash attention ----------
// grid dim3(B*H=64, 16). Balanced qt map: y0=y&3, g=y>>2;
// qt = g==0 ? 15-y0 : g==1 ? 8+y0 : g==2 ? 7-y0 : y0 (per-CU-class work equal).
// block = 256 threads = 4 waves; wave owns 32 q-rows (2 sub-tiles of 16).
// S^T = MFMA(A=K-frag LDS, B=Q-frag regs); lsum = P @ ones via MFMA.
// Per-(m,kt): fully-masked -> zero store, NO MFMA; clean -> no mask VALU;
// diagonal -> per-element select. Conditions scalarized via readfirstlane.
__global__ __launch_bounds__(256, 2) void attn_fwd(
    const short* __restrict__ Q, const short* __restrict__ K,
    const short* __restrict__ V, short* __restrict__ O)
{
    __shared__ short Ks[64][72];    // [key][d]
    __shared__ short Vt[64][72];    // [d][key]
    __shared__ short Ps[128][72];   // [q][key] (wave-private 32-row stripes)
    const int tid = threadIdx.x;
    const int wave = tid >> 6, lane = tid & 63;
    const int quad = lane >> 4, l16 = lane & 15;
    const int bh = blockIdx.x;
    const int b = bh >> 4, h = bh & 15;
    const int y = blockIdx.y, y0 = y & 3, g = y >> 2;
    const int qt = (g == 0) ? 15 - y0 : (g == 1) ? 8 + y0 : (g == 2) ? 7 - y0 : y0;
    const int qbase = qt * 128;
    const short* Qh = Q + (size_t)bh * SEQ * HEAD_DIM;
    const short* Kh = K + (size_t)bh * SEQ * HEAD_DIM;
    const short* Vh = V + (size_t)bh * SEQ * HEAD_DIM;

    const float C1 = 0.125f * 1.44269504f;   // scale * log2(e)
    const float C2 = 14.4269504f;            // 10 * log2(e)

    // constant bf16 1.0 B-fragment for the row-sum MFMA
    bf16x8 onesf;
#pragma unroll
    for (int e = 0; e < 8; ++e) onesf[e] = (short)0x3F80;

    bf16x8 qf[2][2];                    // [m][st] B-frag: Q[q=l16][k=quad*8+j]
#pragma unroll
    for (int m = 0; m < 2; ++m)
#pragma unroll
        for (int st = 0; st < 2; ++st)
            qf[m][st] = *(const bf16x8*)(Qh + (size_t)(qbase + wave * 32 + m * 16 + l16) * HEAD_DIM + st * 32 + quad * 8);

    f32x4 o[2][4] = {};                 // [m][dtile], rows quad*4+r (= local q)
    f32x4 osum[2] = {};                 // P@1 row-sums, same row layout as o

    const int subw = qbase + wave * 32;                  // wave's first q row
    const int subS = __builtin_amdgcn_readfirstlane(subw);

    const int kr = tid >> 2, kc = (tid & 3) * 16;        // K staging: row, col
    const int vk = (tid & 31) * 2, vd = (tid >> 5) * 8;  // V staging: key pair, d base

    const int ntiles = 2 * qt + 2;
    // preload tile 0
    int4 kv0 = *(const int4*)(Kh + (size_t)kr * HEAD_DIM + kc);
    int4 kv1 = *(const int4*)(Kh + (size_t)kr * HEAD_DIM + kc + 8);
    int4 vv0 = *(const int4*)(Vh + (size_t)vk * HEAD_DIM + vd);
    int4 vv1 = *(const int4*)(Vh + (size_t)(vk + 1) * HEAD_DIM + vd);

    for (int j = 0; j < ntiles; ++j) {
        const int kb = j * 64;
        __syncthreads();                 // prior tile fully consumed
        *(int4*)&Ks[kr][kc] = kv0;
        *(int4*)&Ks[kr][kc + 8] = kv1;
        {   // V transpose: v_perm pack (1 op/word), paired b32 writes
            const uint* pa = (const uint*)&vv0;
            const uint* pb = (const uint*)&vv1;
#pragma unroll
            for (int e = 0; e < 4; ++e) {
                uint lo = __builtin_amdgcn_perm(pb[e], pa[e], 0x05040100u);
                uint hi = __builtin_amdgcn_perm(pb[e], pa[e], 0x07060302u);
                *(uint*)&Vt[vd + 2 * e][vk] = lo;
                *(uint*)&Vt[vd + 2 * e + 1][vk] = hi;
            }
        }
        __syncthreads();

        // rotated prefetch: next tile's K/V loads overlap this tile's compute
        if (j + 1 < ntiles) {
            const int kbn = kb + 64;
            kv0 = *(const int4*)(Kh + (size_t)(kbn + kr) * HEAD_DIM + kc);
            kv1 = *(const int4*)(Kh + (size_t)(kbn + kr) * HEAD_DIM + kc + 8);
            vv0 = *(const int4*)(Vh + (size_t)(kbn + vk) * HEAD_DIM + vd);
            vv1 = *(const int4*)(Vh + (size_t)(kbn + vk + 1) * HEAD_DIM + vd);
        }

        if (kb > subS + 31) continue;   // whole wave's rows masked for this tile

        // fused per-kt: S^T MFMA + softmax + P store.
        // S^T[key][q]: MFMA(A=K-frag, B=Q-frag); row=key=quad*4+r, col=q=l16.
        {
            const int prowb = wave * 32 + l16;
#pragma unroll
            for (int kt = 0; kt < 4; ++kt) {
                const int kbkt = kb + kt * 16;      // scalar
                bf16x8 kf0, kf1;
                if (kbkt <= subS + 31) {            // needed by at least one m
                    kf0 = *(const bf16x8*)&Ks[kt * 16 + l16][quad * 8];
                    kf1 = *(const bf16x8*)&Ks[kt * 16 + l16][32 + quad * 8];
                }
#pragma unroll
                for (int m = 0; m < 2; ++m) {
                    const int sub = subS + m * 16;  // scalar
                    uint2 u;
                    if (kbkt > sub + 15) {          // fully masked: skip MFMA too
                        u.x = 0u; u.y = 0u;
                    } else {
                        f32x4 tt = {0.f, 0.f, 0.f, 0.f};
                        tt = __builtin_amdgcn_mfma_f32_16x16x32_bf16(kf0, qf[m][0], tt, 0, 0, 0);
                        tt = __builtin_amdgcn_mfma_f32_16x16x32_bf16(kf1, qf[m][1], tt, 0, 0, 0);
                        float p[4];
                        if (kbkt + 15 <= sub) {     // fully unmasked: no mask VALU
#pragma unroll
                            for (int r = 0; r < 4; ++r)
                                p[r] = __builtin_exp2f(__builtin_fmaf(tt[r], C1, -C2));
                        } else {                    // diagonal subtile
                            const int qrow = sub + l16;
#pragma unroll
                            for (int r = 0; r < 4; ++r) {
                                float a = __builtin_fmaf(tt[r], C1, -C2);
                                if (kbkt + quad * 4 + r > qrow) a = -1e30f;
                                p[r] = __builtin_exp2f(a);
                            }
                        }
                        u.x = packtr(p[0], p[1]); u.y = packtr(p[2], p[3]);
                    }
                    *(uint2*)&Ps[prowb + m * 16][kt * 16 + quad * 4] = u;
                }
            }
        }
        // O += P @ V ; osum += P @ 1 (all intra-wave; st=1 skipped when
        // keys 32-63 are fully masked for this wave's rows)
#pragma unroll
        for (int st = 0; st < 2; ++st) {
            if (st == 1 && kb + 32 > subS + 31) break;
            bf16x8 pf0 = *(const bf16x8*)&Ps[wave * 32 + l16][st * 32 + quad * 8];
            bf16x8 pf1 = *(const bf16x8*)&Ps[wave * 32 + 16 + l16][st * 32 + quad * 8];
            __builtin_amdgcn_s_setprio(1);
            osum[0] = __builtin_amdgcn_mfma_f32_16x16x32_bf16(pf0, onesf, osum[0], 0, 0, 0);
            osum[1] = __builtin_amdgcn_mfma_f32_16x16x32_bf16(pf1, onesf, osum[1], 0, 0, 0);
#pragma unroll
            for (int dt = 0; dt < 4; ++dt) {
                bf16x8 vf = *(const bf16x8*)&Vt[dt * 16 + l16][st * 32 + quad * 8];
                o[0][dt] = __builtin_amdgcn_mfma_f32_16x16x32_bf16(pf0, vf, o[0][dt], 0, 0, 0);
                o[1][dt] = __builtin_amdgcn_mfma_f32_16x16x32_bf16(pf1, vf, o[1][dt], 0, 0, 0);
            }
            __builtin_amdgcn_s_setprio(0);
        }
    }

    // epilogue: per-lane normalize, store
#pragma unroll
    for (int m = 0; m < 2; ++m) {
#pragma unroll
        for (int r = 0; r < 4; ++r) {
            float inv = 1.f / osum[m][r];
            int t = qbase + wave * 32 + m * 16 + quad * 4 + r;
            size_t base = ((size_t)b * SEQ + t) * D_MODEL + h * HEAD_DIM;
#pragma unroll
            for (int dt = 0; dt < 4; ++dt)
                O[base + dt * 16 + l16] = f2bf(o[m][dt][r] * inv);
        }
    }
}

extern "C" void kernel_launch(void* const* d_in, const int* in_sizes, int n_in,
                              void* d_out, int out_size, void* d_ws, size_t ws_size,
                              hipStream_t stream)
{
    const float* x     = (const float*)d_in[0];
    const float* w_qkv = (const float*)d_in[1];
    const float* b_qkv = (const float*)d_in[2];
    const float* w_out = (const float*)d_in[3];
    const float* b_out = (const float*)d_in[4];
    float* out = (float*)d_out;

    const int NX = BATCH * SEQ * D_MODEL;          // 8388608
    const int NWQ = 3 * D_MODEL * D_MODEL;
    const int NWO = D_MODEL * D_MODEL;
    const size_t HE = (size_t)BATCH * N_HEADS * SEQ * HEAD_DIM;

    short* xb    = (short*)d_ws;
    short* wqkvb = xb + NX;
    short* woutb = wqkvb + NWQ;
    short* qp    = woutb + NWO;
    short* kp    = qp + HE;
    short* vp    = kp + HE;
    short* ho    = xb;                   // aliases xb (dead after GEMM1)

    const int M = BATCH * SEQ;  // 8192

    // merged cvt: xb|wqkvb|woutb are contiguous in ws; one launch
    cvt3_bf16<<<(NX + NWQ + NWO) / 1024, 256, 0, stream>>>(
        x, w_qkv, w_out, xb, NX / 4, (NX + NWQ) / 4);

    gemm_bt<1><<<dim3(3 * D_MODEL / 128, M / 256), 256, 0, stream>>>(
        xb, wqkvb, b_qkv, nullptr, M, 3 * D_MODEL, D_MODEL, qp, kp, vp);

    attn_fwd<<<dim3(BATCH * N_HEADS, SEQ / 128), 256, 0, stream>>>(qp, kp, vp, ho);

    gemm_bt<0><<<dim3(D_MODEL / 128, M / 256), 256, 0, stream>>>(
        ho, woutb, b_out, out, M, D_MODEL, D_MODEL, nullptr, nullptr, nullptr);
}